// Round 4
// baseline (3739.672 us; speedup 1.0000x reference)
//
#include <hip/hip_runtime.h>

#define BB 4
#define NN 8192
#define PP 2048
#define KNB 16
#define CIN 64
#define COUT 128

__device__ __forceinline__ float elu(float x) { return x > 0.0f ? x : expm1f(x); }

// monotone float->uint key (handles negative floats from cancellation)
__device__ __forceinline__ unsigned fkey(float d) {
    unsigned u = __float_as_uint(d);
    unsigned m = (unsigned)((int)u >> 31);
    return u ^ (m | 0x80000000u);
}

// spread low 10 bits of v to every 3rd bit (Morton)
__device__ __forceinline__ unsigned mspread(unsigned v) {
    v &= 0x3FFu;
    v = (v | (v << 16)) & 0x030000FFu;
    v = (v | (v << 8))  & 0x0300F00Fu;
    v = (v | (v << 4))  & 0x030C30C3u;
    v = (v | (v << 2))  & 0x09249249u;
    return v;
}

// ---------------------------------------------------------------------------
// FPS v4: 512 threads, 16 pts/thread, Morton-sorted groups + triangle-
// inequality pruning (QuickFPS-style). Exact IEEE distance path preserved;
// prune bound is conservatively margined so selections match the reference
// bit-exactly. One barrier per round (double-buffered partials).
// ---------------------------------------------------------------------------
__global__ __launch_bounds__(512) void fps_kernel(const float* __restrict__ pts,
                                                  float* __restrict__ rep) {
    const int b = blockIdx.x;
    const int t = threadIdx.x;
    const int lane = t & 63, wave = t >> 6;   // 8 waves

    __shared__ float spx[NN];
    __shared__ float spy[NN];
    __shared__ float spz[NN];
    __shared__ unsigned sbuf[NN];
    __shared__ unsigned long long partk[2][8];

    const float* pb = pts + (size_t)b * NN * 3;
    for (int i = t; i < NN; i += 512) {
        spx[i] = pb[3 * i + 0];
        spy[i] = pb[3 * i + 1];
        spz[i] = pb[3 * i + 2];
    }
    __syncthreads();

    // ---- Morton keys: 6 bits/dim over [-4,4], code<<13 | idx (31 bits) ----
#pragma unroll
    for (int r = 0; r < 16; ++r) {
        int i = t * 16 + r;
        int qx = min(max((int)((spx[i] + 4.0f) * 8.0f), 0), 63);
        int qy = min(max((int)((spy[i] + 4.0f) * 8.0f), 0), 63);
        int qz = min(max((int)((spz[i] + 4.0f) * 8.0f), 0), 63);
        unsigned code = mspread((unsigned)qx) | (mspread((unsigned)qy) << 1)
                      | (mspread((unsigned)qz) << 2);
        sbuf[i] = (code << 13) | (unsigned)i;
    }
    __syncthreads();

    // ---- bitonic sort of 8192 u32 keys (512 thr x 8 pairs per substage) ----
    for (unsigned kk2 = 2; kk2 <= (unsigned)NN; kk2 <<= 1) {
        for (unsigned j = kk2 >> 1; j > 0; j >>= 1) {
#pragma unroll
            for (int m = 0; m < 8; ++m) {
                unsigned i = (unsigned)t + (unsigned)m * 512u;     // pair id
                unsigned low = i & (j - 1u);
                unsigned a = ((i & ~(j - 1u)) << 1) | low;
                unsigned p2 = a | j;
                unsigned ka = sbuf[a], kb = sbuf[p2];
                bool up = ((a & kk2) == 0u);
                if ((ka > kb) == up) { sbuf[a] = kb; sbuf[p2] = ka; }
            }
            __syncthreads();
        }
    }

    // ---- gather my 16 Morton-contiguous points, group stats ----
    int orig[16];
    float px[16], py[16], pz[16], dist[16];
#pragma unroll
    for (int r = 0; r < 16; ++r) {
        int o = (int)(sbuf[t * 16 + r] & 0x1FFFu);
        orig[r] = o;
        px[r] = spx[o]; py[r] = spy[o]; pz[r] = spz[o];
        dist[r] = 1e10f;
    }
    float gx = 0.f, gy = 0.f, gz = 0.f;
#pragma unroll
    for (int r = 0; r < 16; ++r) { gx += px[r]; gy += py[r]; gz += pz[r]; }
    gx *= (1.0f / 16.0f); gy *= (1.0f / 16.0f); gz *= (1.0f / 16.0f);
    float r2m = 0.f;
#pragma unroll
    for (int r = 0; r < 16; ++r) {
        float ex = px[r] - gx, ey = py[r] - gy, ez = pz[r] - gz;
        r2m = fmaxf(r2m, ex * ex + ey * ey + ez * ez);
    }
    const float rg = sqrtf(r2m) * 1.00002f + 1e-12f;

    // initial cached group key: all dists 1e10, min orig idx wins ties
    int minorig = orig[0];
#pragma unroll
    for (int r = 1; r < 16; ++r) minorig = min(minorig, orig[r]);
    unsigned long long gkey = ((unsigned long long)__float_as_uint(1e10f) << 32)
                            | (unsigned)(8191 - minorig);

    float cx = spx[0], cy = spy[0], cz = spz[0];
    if (t == 0) {
        rep[(size_t)b * PP * 3 + 0] = cx;
        rep[(size_t)b * PP * 3 + 1] = cy;
        rep[(size_t)b * PP * 3 + 2] = cz;
    }

    int buf = 0;
    for (int s = 1; s < PP; ++s) {
        // conservative triangle-inequality prune (margins >> fp rounding)
        float ddx = cx - gx, ddy = cy - gy, ddz = cz - gz;
        float D = ddx * ddx + ddy * ddy + ddz * ddz;
        float sD = sqrtf(D) * 0.99999f;
        float diff = sD - rg;
        float gmaxf = __uint_as_float((unsigned)(gkey >> 32));
        bool prune = (diff > 0.0f) && (diff * diff * 0.9999f > gmaxf);

        if (!prune) {
            float bv = -1.0f; int bi = 0x7FFFFFFF;
#pragma unroll
            for (int r = 0; r < 16; ++r) {
                float dx = __fsub_rn(px[r], cx);
                float dy = __fsub_rn(py[r], cy);
                float dz = __fsub_rn(pz[r], cz);
                float d = __fadd_rn(__fadd_rn(__fmul_rn(dx, dx), __fmul_rn(dy, dy)),
                                    __fmul_rn(dz, dz));
                float nd = fminf(dist[r], d);
                dist[r] = nd;
                bool take = (nd > bv) || ((nd == bv) && (orig[r] < bi));
                bi = take ? orig[r] : bi;
                bv = take ? nd : bv;
            }
            gkey = ((unsigned long long)__float_as_uint(bv) << 32)
                 | (unsigned)(8191 - bi);
        }

        unsigned long long k = gkey;
#pragma unroll
        for (int off = 32; off >= 1; off >>= 1) {
            unsigned long long o = __shfl_xor(k, off);
            k = o > k ? o : k;
        }
        if (lane == 0) partk[buf][wave] = k;
        __syncthreads();
        unsigned long long kk = partk[buf][0];
#pragma unroll
        for (int q = 1; q < 8; ++q) {
            unsigned long long c = partk[buf][q];
            kk = c > kk ? c : kk;
        }
        int widx = 8191 - (int)(unsigned)(kk & 0xFFFFFFFFULL);
        cx = spx[widx]; cy = spy[widx]; cz = spz[widx];
        if (t == 0) {
            float* rp = rep + ((size_t)b * PP + s) * 3;
            rp[0] = cx; rp[1] = cy; rp[2] = cz;
        }
        buf ^= 1;
    }
}

// ---------------------------------------------------------------------------
// Dense: fts_d = elu(fts @ W + b). One wave per row, lane = output channel.
// ---------------------------------------------------------------------------
__global__ __launch_bounds__(256) void dense_kernel(const float* __restrict__ fts,
                                                    const float* __restrict__ W,
                                                    const float* __restrict__ bias,
                                                    float* __restrict__ out) {
    const int row = blockIdx.x * 4 + (threadIdx.x >> 6);
    const int c = threadIdx.x & 63;
    float v = fts[(size_t)row * 64 + c];
    float acc = bias[c];
#pragma unroll 8
    for (int k = 0; k < 64; ++k) acc = fmaf(__shfl(v, k), W[k * 64 + c], acc);
    out[(size_t)row * 64 + c] = elu(acc);
}

// ---------------------------------------------------------------------------
// KNN: one wave per rep point; per-lane sorted top-16 of 128 candidates via
// u64 keys (flipped dist bits << 32 | idx); 16-round lex-min merge-extract.
// Exact IEEE ops, same evaluation order as reference: (a - 2b) + c.
// ---------------------------------------------------------------------------
__global__ __launch_bounds__(256) void knn_kernel(const float* __restrict__ pts,
                                                  const float* __restrict__ rep,
                                                  int* __restrict__ kidx) {
    const int wid = blockIdx.x * 4 + (threadIdx.x >> 6);
    const int lane = threadIdx.x & 63;
    const int b = wid >> 11;
    const float* pb = pts + (size_t)b * NN * 3;

    float rx = rep[(size_t)wid * 3 + 0];
    float ry = rep[(size_t)wid * 3 + 1];
    float rz = rep[(size_t)wid * 3 + 2];
    float a = __fadd_rn(__fadd_rn(__fmul_rn(rx, rx), __fmul_rn(ry, ry)), __fmul_rn(rz, rz));

    unsigned long long key[16];
#pragma unroll
    for (int s = 0; s < 16; ++s) key[s] = ~0ULL;

    for (int j = lane; j < NN; j += 64) {
        float qx = pb[j * 3 + 0], qy = pb[j * 3 + 1], qz = pb[j * 3 + 2];
        float cc = __fadd_rn(__fadd_rn(__fmul_rn(qx, qx), __fmul_rn(qy, qy)), __fmul_rn(qz, qz));
        float bs = __fadd_rn(__fadd_rn(__fmul_rn(rx, qx), __fmul_rn(ry, qy)), __fmul_rn(rz, qz));
        float d2 = __fadd_rn(__fsub_rn(a, __fmul_rn(2.0f, bs)), cc);
        unsigned long long nk = ((unsigned long long)fkey(d2) << 32) | (unsigned)j;
        if (nk < key[15]) {
            key[15] = nk;
#pragma unroll
            for (int s2 = 15; s2 > 0; --s2) {
                unsigned long long u = key[s2 - 1], w = key[s2];
                bool sw = w < u;
                key[s2 - 1] = sw ? w : u;
                key[s2] = sw ? u : w;
            }
        }
    }

    int outv = 0;
#pragma unroll 1
    for (int r = 0; r < 16; ++r) {
        unsigned long long h = key[0];
#pragma unroll
        for (int off = 1; off < 64; off <<= 1) {
            unsigned long long o = __shfl_xor(h, off);
            h = (o < h) ? o : h;
        }
        if (lane == r) outv = (int)(unsigned)(h & 0xFFFFFFFFull);
        if (key[0] == h) {  // unique winner (idx embedded in key)
#pragma unroll
            for (int s2 = 0; s2 < 15; ++s2) key[s2] = key[s2 + 1];
            key[15] = ~0ULL;
        }
    }
    if (lane < 16) kidx[(size_t)wid * 16 + lane] = outv;
}

// ---------------------------------------------------------------------------
// XConv + SepConv: one 64-thread block per rep point, all staged through LDS.
// ---------------------------------------------------------------------------
__global__ __launch_bounds__(64) void xconv_kernel(
    const float* __restrict__ pts, const float* __restrict__ rep,
    const float* __restrict__ ftsd, const int* __restrict__ kidx,
    const float* __restrict__ d1W, const float* __restrict__ d1b,
    const float* __restrict__ d2W, const float* __restrict__ d2b,
    const float* __restrict__ convW, const float* __restrict__ convb,
    const float* __restrict__ dw1W, const float* __restrict__ dw1b,
    const float* __restrict__ dw2W, const float* __restrict__ dw2b,
    const float* __restrict__ sdwW, const float* __restrict__ sdwb,
    const float* __restrict__ spwW, const float* __restrict__ spwb,
    float* __restrict__ outp) {
    const int bp = blockIdx.x;
    const int b = bp >> 11;
    const int t = threadIdx.x;

    __shared__ float pl[16][3];
    __shared__ int nidx[16];
    __shared__ float fcat[16][96];   // cols 0..31 = lift, 32..95 = gathered fts_d
    __shared__ float A1[16][32];
    __shared__ float Xm[16][17];
    __shared__ float X2[16][17];
    __shared__ float X3[16][17];
    __shared__ float fX[16][97];
    __shared__ float dsep[192];

    if (t < 16) {
        int id = kidx[(size_t)bp * 16 + t];
        nidx[t] = id;
        const float* q = pts + ((size_t)b * NN + id) * 3;
        const float* rr = rep + (size_t)bp * 3;
        pl[t][0] = q[0] - rr[0];
        pl[t][1] = q[1] - rr[1];
        pl[t][2] = q[2] - rr[2];
    }
    __syncthreads();

    // gather neighbor features (coalesced: lane = channel)
#pragma unroll
    for (int k = 0; k < 16; ++k)
        fcat[k][32 + t] = ftsd[((size_t)b * NN + nidx[k]) * 64 + t];

    // lift MLP layer 1: [16,3] @ [3,32]
#pragma unroll
    for (int r2 = 0; r2 < 8; ++r2) {
        int e = t + 64 * r2; int k = e >> 5, j = e & 31;
        float acc = d1b[j];
        acc = fmaf(pl[k][0], d1W[j], acc);
        acc = fmaf(pl[k][1], d1W[32 + j], acc);
        acc = fmaf(pl[k][2], d1W[64 + j], acc);
        A1[k][j] = elu(acc);
    }
    __syncthreads();

    // lift MLP layer 2: [16,32] @ [32,32] -> fcat cols 0..31
#pragma unroll
    for (int r2 = 0; r2 < 8; ++r2) {
        int e = t + 64 * r2; int k = e >> 5, j = e & 31;
        float acc = d2b[j];
#pragma unroll
        for (int c = 0; c < 32; ++c) acc = fmaf(A1[k][c], d2W[c * 32 + j], acc);
        fcat[k][j] = elu(acc);
    }
    __syncthreads();

    // X matrix: X[o] = elu(sum_{c,k} pl[k][c]*convW[o][c][k] + convb[o]), o=0..255
#pragma unroll
    for (int r2 = 0; r2 < 4; ++r2) {
        int o = t + 64 * r2;
        float acc = convb[o];
#pragma unroll
        for (int c = 0; c < 3; ++c)
#pragma unroll
            for (int k = 0; k < 16; ++k)
                acc = fmaf(pl[k][c], convW[(o * 3 + c) * 16 + k], acc);
        Xm[o >> 4][o & 15] = elu(acc);
    }
    __syncthreads();

    // dw1: out[j][m] = elu(sum_i Xm[i][j]*dw1W[j][m][i] + dw1b[j][m])
#pragma unroll
    for (int r2 = 0; r2 < 4; ++r2) {
        int e = t + 64 * r2; int j = e >> 4, m = e & 15;
        float acc = dw1b[e];
#pragma unroll
        for (int i = 0; i < 16; ++i) acc = fmaf(Xm[i][j], dw1W[e * 16 + i], acc);
        X2[j][m] = elu(acc);
    }
    __syncthreads();

    // dw2 (no ELU)
#pragma unroll
    for (int r2 = 0; r2 < 4; ++r2) {
        int e = t + 64 * r2; int j = e >> 4, m = e & 15;
        float acc = dw2b[e];
#pragma unroll
        for (int i = 0; i < 16; ++i) acc = fmaf(X2[i][j], dw2W[e * 16 + i], acc);
        X3[j][m] = acc;
    }
    __syncthreads();

    // fts_X[a][c] = sum_b X3[a][b] * fcat[b][c]
#pragma unroll
    for (int r2 = 0; r2 < 24; ++r2) {
        int e = t + 64 * r2; int a = e & 15, c = e >> 4;
        float acc = 0.0f;
#pragma unroll
        for (int q = 0; q < 16; ++q) acc = fmaf(X3[a][q], fcat[q][c], acc);
        fX[a][c] = acc;
    }
    __syncthreads();

    // separable depthwise: d[c][m] = sum_k fX[k][c]*sdwW[c][m][k] + sdwb[c][m]
#pragma unroll
    for (int r2 = 0; r2 < 3; ++r2) {
        int e = t + 64 * r2; int c = e >> 1;
        float acc = sdwb[e];
#pragma unroll
        for (int k = 0; k < 16; ++k) acc = fmaf(fX[k][c], sdwW[e * 16 + k], acc);
        dsep[e] = acc;
    }
    __syncthreads();

    // pointwise: out[o] = elu(sum_{c,m} d[c][m]*spwW[o][c][m] + spwb[o])
#pragma unroll
    for (int r2 = 0; r2 < 2; ++r2) {
        int o = t + 64 * r2;
        float acc = spwb[o];
#pragma unroll 16
        for (int e2 = 0; e2 < 192; ++e2) acc = fmaf(dsep[e2], spwW[o * 192 + e2], acc);
        outp[(size_t)bp * 128 + o] = elu(acc);
    }
}

extern "C" void kernel_launch(void* const* d_in, const int* in_sizes, int n_in,
                              void* d_out, int out_size, void* d_ws, size_t ws_size,
                              hipStream_t stream) {
    const float* pts    = (const float*)d_in[0];
    const float* fts    = (const float*)d_in[1];
    const float* denseW = (const float*)d_in[2];
    const float* denseb = (const float*)d_in[3];
    const float* d1W    = (const float*)d_in[4];
    const float* d1b    = (const float*)d_in[5];
    const float* d2W    = (const float*)d_in[6];
    const float* d2b    = (const float*)d_in[7];
    const float* convW  = (const float*)d_in[8];
    const float* convb  = (const float*)d_in[9];
    const float* dw1W   = (const float*)d_in[10];
    const float* dw1b   = (const float*)d_in[11];
    const float* dw2W   = (const float*)d_in[12];
    const float* dw2b   = (const float*)d_in[13];
    const float* sdwW   = (const float*)d_in[14];
    const float* sdwb   = (const float*)d_in[15];
    const float* spwW   = (const float*)d_in[16];
    const float* spwb   = (const float*)d_in[17];

    float* rep  = (float*)d_out;                       // [B,P,3]
    float* outp = (float*)d_out + (size_t)BB * PP * 3; // [B,P,128]

    float* ftsd = (float*)d_ws;                                            // B*N*64 f32
    int*   kidx = (int*)((char*)d_ws + (size_t)BB * NN * CIN * sizeof(float)); // B*P*16 i32

    dense_kernel<<<BB * NN / 4, 256, 0, stream>>>(fts, denseW, denseb, ftsd);
    fps_kernel<<<BB, 512, 0, stream>>>(pts, rep);
    knn_kernel<<<BB * PP / 4, 256, 0, stream>>>(pts, rep, kidx);
    xconv_kernel<<<BB * PP, 64, 0, stream>>>(pts, rep, ftsd, kidx,
                                             d1W, d1b, d2W, d2b, convW, convb,
                                             dw1W, dw1b, dw2W, dw2b,
                                             sdwW, sdwb, spwW, spwb, outp);
}

// Round 5
// 2615.362 us; speedup vs baseline: 1.4299x; 1.4299x over previous
//
#include <hip/hip_runtime.h>

#define BB 4
#define NN 8192
#define PP 2048
#define KNB 16
#define CIN 64
#define COUT 128

__device__ __forceinline__ float elu(float x) { return x > 0.0f ? x : expm1f(x); }

// monotone float->uint key (handles negative floats from cancellation)
__device__ __forceinline__ unsigned fkey(float d) {
    unsigned u = __float_as_uint(d);
    unsigned m = (unsigned)((int)u >> 31);
    return u ^ (m | 0x80000000u);
}

// ---------------------------------------------------------------------------
// FPS v5: v3 structure (512 threads, 16 idx-ordered pts/thread, LDS mirror,
// one barrier/round) with the cross-lane reduce rebuilt:
//   - wave reduce = plain f32 max butterfly (1 swizzle + 1 v_max per hop)
//   - winner index recovered once via ballot + ffs + single shuffle
// replacing the 64-bit (2 swizzle + cmp64 + 2 cndmask) carry at every hop.
// Tie semantics preserved: lane order == index order, ballot picks lowest
// lane == lowest index; cross-wave scan keeps u64 (bits<<32 | 8191-idx).
// Exact IEEE ops (no FMA) in distance path to match reference selection.
// ---------------------------------------------------------------------------
__global__ __launch_bounds__(512) void fps_kernel(const float* __restrict__ pts,
                                                  float* __restrict__ rep) {
    const int b = blockIdx.x;
    const int t = threadIdx.x;
    const int lane = t & 63, wave = t >> 6;   // 8 waves

    __shared__ float spx[NN];
    __shared__ float spy[NN];
    __shared__ float spz[NN];
    __shared__ unsigned long long partk[2][8];

    const float* pb = pts + (size_t)b * NN * 3;
    for (int i = t; i < NN; i += 512) {
        spx[i] = pb[3 * i + 0];
        spy[i] = pb[3 * i + 1];
        spz[i] = pb[3 * i + 2];
    }
    __syncthreads();

    float px[16], py[16], pz[16], dist[16];
#pragma unroll
    for (int r = 0; r < 16; ++r) {
        px[r] = spx[t * 16 + r];
        py[r] = spy[t * 16 + r];
        pz[r] = spz[t * 16 + r];
        dist[r] = 1e10f;
    }

    float cx = spx[0], cy = spy[0], cz = spz[0];
    if (t == 0) {
        rep[(size_t)b * PP * 3 + 0] = cx;
        rep[(size_t)b * PP * 3 + 1] = cy;
        rep[(size_t)b * PP * 3 + 2] = cz;
    }

    int buf = 0;
    for (int s = 1; s < PP; ++s) {
        float bv = -1.0f; int bi = 0;
#pragma unroll
        for (int r = 0; r < 16; ++r) {
            float dx = __fsub_rn(px[r], cx);
            float dy = __fsub_rn(py[r], cy);
            float dz = __fsub_rn(pz[r], cz);
            float d = __fadd_rn(__fadd_rn(__fmul_rn(dx, dx), __fmul_rn(dy, dy)), __fmul_rn(dz, dz));
            float nd = fminf(dist[r], d);
            dist[r] = nd;
            bool tk = nd > bv;            // strict >: first-max (lowest r = lowest idx)
            bi = tk ? (t * 16 + r) : bi;
            bv = fmaxf(nd, bv);
        }

        // ---- wave reduce: f32 max butterfly (cheapest possible hop) ----
        float wmax = bv;
#pragma unroll
        for (int off = 32; off >= 1; off >>= 1)
            wmax = fmaxf(wmax, __shfl_xor(wmax, off));
        // winner index: lowest lane attaining wmax == lowest idx (lane==idx order)
        unsigned long long mask = __ballot(bv == wmax);
        int wl = __ffsll(mask) - 1;
        int wbi = __shfl(bi, wl);

        if (lane == 0)
            partk[buf][wave] = ((unsigned long long)__float_as_uint(wmax) << 32)
                             | (unsigned)(8191 - wbi);
        __syncthreads();

        // all threads scan the 8 partials (broadcast reads) -> winner everywhere
        unsigned long long kk = partk[buf][0];
#pragma unroll
        for (int q = 1; q < 8; ++q) {
            unsigned long long c = partk[buf][q];
            kk = c > kk ? c : kk;
        }
        int widx = 8191 - (int)(unsigned)(kk & 0xFFFFFFFFULL);
        cx = spx[widx]; cy = spy[widx]; cz = spz[widx];
        if (t == 0) {
            float* rp = rep + ((size_t)b * PP + s) * 3;
            rp[0] = cx; rp[1] = cy; rp[2] = cz;
        }
        buf ^= 1;
    }
}

// ---------------------------------------------------------------------------
// Dense: fts_d = elu(fts @ W + b). One wave per row, lane = output channel.
// ---------------------------------------------------------------------------
__global__ __launch_bounds__(256) void dense_kernel(const float* __restrict__ fts,
                                                    const float* __restrict__ W,
                                                    const float* __restrict__ bias,
                                                    float* __restrict__ out) {
    const int row = blockIdx.x * 4 + (threadIdx.x >> 6);
    const int c = threadIdx.x & 63;
    float v = fts[(size_t)row * 64 + c];
    float acc = bias[c];
#pragma unroll 8
    for (int k = 0; k < 64; ++k) acc = fmaf(__shfl(v, k), W[k * 64 + c], acc);
    out[(size_t)row * 64 + c] = elu(acc);
}

// ---------------------------------------------------------------------------
// KNN: one wave per rep point; per-lane sorted top-16 of 128 candidates via
// u64 keys (flipped dist bits << 32 | idx); 16-round lex-min merge-extract.
// Exact IEEE ops, same evaluation order as reference: (a - 2b) + c.
// ---------------------------------------------------------------------------
__global__ __launch_bounds__(256) void knn_kernel(const float* __restrict__ pts,
                                                  const float* __restrict__ rep,
                                                  int* __restrict__ kidx) {
    const int wid = blockIdx.x * 4 + (threadIdx.x >> 6);
    const int lane = threadIdx.x & 63;
    const int b = wid >> 11;
    const float* pb = pts + (size_t)b * NN * 3;

    float rx = rep[(size_t)wid * 3 + 0];
    float ry = rep[(size_t)wid * 3 + 1];
    float rz = rep[(size_t)wid * 3 + 2];
    float a = __fadd_rn(__fadd_rn(__fmul_rn(rx, rx), __fmul_rn(ry, ry)), __fmul_rn(rz, rz));

    unsigned long long key[16];
#pragma unroll
    for (int s = 0; s < 16; ++s) key[s] = ~0ULL;

    for (int j = lane; j < NN; j += 64) {
        float qx = pb[j * 3 + 0], qy = pb[j * 3 + 1], qz = pb[j * 3 + 2];
        float cc = __fadd_rn(__fadd_rn(__fmul_rn(qx, qx), __fmul_rn(qy, qy)), __fmul_rn(qz, qz));
        float bs = __fadd_rn(__fadd_rn(__fmul_rn(rx, qx), __fmul_rn(ry, qy)), __fmul_rn(rz, qz));
        float d2 = __fadd_rn(__fsub_rn(a, __fmul_rn(2.0f, bs)), cc);
        unsigned long long nk = ((unsigned long long)fkey(d2) << 32) | (unsigned)j;
        if (nk < key[15]) {
            key[15] = nk;
#pragma unroll
            for (int s2 = 15; s2 > 0; --s2) {
                unsigned long long u = key[s2 - 1], w = key[s2];
                bool sw = w < u;
                key[s2 - 1] = sw ? w : u;
                key[s2] = sw ? u : w;
            }
        }
    }

    int outv = 0;
#pragma unroll 1
    for (int r = 0; r < 16; ++r) {
        unsigned long long h = key[0];
#pragma unroll
        for (int off = 1; off < 64; off <<= 1) {
            unsigned long long o = __shfl_xor(h, off);
            h = (o < h) ? o : h;
        }
        if (lane == r) outv = (int)(unsigned)(h & 0xFFFFFFFFull);
        if (key[0] == h) {  // unique winner (idx embedded in key)
#pragma unroll
            for (int s2 = 0; s2 < 15; ++s2) key[s2] = key[s2 + 1];
            key[15] = ~0ULL;
        }
    }
    if (lane < 16) kidx[(size_t)wid * 16 + lane] = outv;
}

// ---------------------------------------------------------------------------
// XConv + SepConv: one 64-thread block per rep point, all staged through LDS.
// ---------------------------------------------------------------------------
__global__ __launch_bounds__(64) void xconv_kernel(
    const float* __restrict__ pts, const float* __restrict__ rep,
    const float* __restrict__ ftsd, const int* __restrict__ kidx,
    const float* __restrict__ d1W, const float* __restrict__ d1b,
    const float* __restrict__ d2W, const float* __restrict__ d2b,
    const float* __restrict__ convW, const float* __restrict__ convb,
    const float* __restrict__ dw1W, const float* __restrict__ dw1b,
    const float* __restrict__ dw2W, const float* __restrict__ dw2b,
    const float* __restrict__ sdwW, const float* __restrict__ sdwb,
    const float* __restrict__ spwW, const float* __restrict__ spwb,
    float* __restrict__ outp) {
    const int bp = blockIdx.x;
    const int b = bp >> 11;
    const int t = threadIdx.x;

    __shared__ float pl[16][3];
    __shared__ int nidx[16];
    __shared__ float fcat[16][96];   // cols 0..31 = lift, 32..95 = gathered fts_d
    __shared__ float A1[16][32];
    __shared__ float Xm[16][17];
    __shared__ float X2[16][17];
    __shared__ float X3[16][17];
    __shared__ float fX[16][97];
    __shared__ float dsep[192];

    if (t < 16) {
        int id = kidx[(size_t)bp * 16 + t];
        nidx[t] = id;
        const float* q = pts + ((size_t)b * NN + id) * 3;
        const float* rr = rep + (size_t)bp * 3;
        pl[t][0] = q[0] - rr[0];
        pl[t][1] = q[1] - rr[1];
        pl[t][2] = q[2] - rr[2];
    }
    __syncthreads();

    // gather neighbor features (coalesced: lane = channel)
#pragma unroll
    for (int k = 0; k < 16; ++k)
        fcat[k][32 + t] = ftsd[((size_t)b * NN + nidx[k]) * 64 + t];

    // lift MLP layer 1: [16,3] @ [3,32]
#pragma unroll
    for (int r2 = 0; r2 < 8; ++r2) {
        int e = t + 64 * r2; int k = e >> 5, j = e & 31;
        float acc = d1b[j];
        acc = fmaf(pl[k][0], d1W[j], acc);
        acc = fmaf(pl[k][1], d1W[32 + j], acc);
        acc = fmaf(pl[k][2], d1W[64 + j], acc);
        A1[k][j] = elu(acc);
    }
    __syncthreads();

    // lift MLP layer 2: [16,32] @ [32,32] -> fcat cols 0..31
#pragma unroll
    for (int r2 = 0; r2 < 8; ++r2) {
        int e = t + 64 * r2; int k = e >> 5, j = e & 31;
        float acc = d2b[j];
#pragma unroll
        for (int c = 0; c < 32; ++c) acc = fmaf(A1[k][c], d2W[c * 32 + j], acc);
        fcat[k][j] = elu(acc);
    }
    __syncthreads();

    // X matrix: X[o] = elu(sum_{c,k} pl[k][c]*convW[o][c][k] + convb[o]), o=0..255
#pragma unroll
    for (int r2 = 0; r2 < 4; ++r2) {
        int o = t + 64 * r2;
        float acc = convb[o];
#pragma unroll
        for (int c = 0; c < 3; ++c)
#pragma unroll
            for (int k = 0; k < 16; ++k)
                acc = fmaf(pl[k][c], convW[(o * 3 + c) * 16 + k], acc);
        Xm[o >> 4][o & 15] = elu(acc);
    }
    __syncthreads();

    // dw1: out[j][m] = elu(sum_i Xm[i][j]*dw1W[j][m][i] + dw1b[j][m])
#pragma unroll
    for (int r2 = 0; r2 < 4; ++r2) {
        int e = t + 64 * r2; int j = e >> 4, m = e & 15;
        float acc = dw1b[e];
#pragma unroll
        for (int i = 0; i < 16; ++i) acc = fmaf(Xm[i][j], dw1W[e * 16 + i], acc);
        X2[j][m] = elu(acc);
    }
    __syncthreads();

    // dw2 (no ELU)
#pragma unroll
    for (int r2 = 0; r2 < 4; ++r2) {
        int e = t + 64 * r2; int j = e >> 4, m = e & 15;
        float acc = dw2b[e];
#pragma unroll
        for (int i = 0; i < 16; ++i) acc = fmaf(X2[i][j], dw2W[e * 16 + i], acc);
        X3[j][m] = acc;
    }
    __syncthreads();

    // fts_X[a][c] = sum_b X3[a][b] * fcat[b][c]
#pragma unroll
    for (int r2 = 0; r2 < 24; ++r2) {
        int e = t + 64 * r2; int a = e & 15, c = e >> 4;
        float acc = 0.0f;
#pragma unroll
        for (int q = 0; q < 16; ++q) acc = fmaf(X3[a][q], fcat[q][c], acc);
        fX[a][c] = acc;
    }
    __syncthreads();

    // separable depthwise: d[c][m] = sum_k fX[k][c]*sdwW[c][m][k] + sdwb[c][m]
#pragma unroll
    for (int r2 = 0; r2 < 3; ++r2) {
        int e = t + 64 * r2; int c = e >> 1;
        float acc = sdwb[e];
#pragma unroll
        for (int k = 0; k < 16; ++k) acc = fmaf(fX[k][c], sdwW[e * 16 + k], acc);
        dsep[e] = acc;
    }
    __syncthreads();

    // pointwise: out[o] = elu(sum_{c,m} d[c][m]*spwW[o][c][m] + spwb[o])
#pragma unroll
    for (int r2 = 0; r2 < 2; ++r2) {
        int o = t + 64 * r2;
        float acc = spwb[o];
#pragma unroll 16
        for (int e2 = 0; e2 < 192; ++e2) acc = fmaf(dsep[e2], spwW[o * 192 + e2], acc);
        outp[(size_t)bp * 128 + o] = elu(acc);
    }
}

extern "C" void kernel_launch(void* const* d_in, const int* in_sizes, int n_in,
                              void* d_out, int out_size, void* d_ws, size_t ws_size,
                              hipStream_t stream) {
    const float* pts    = (const float*)d_in[0];
    const float* fts    = (const float*)d_in[1];
    const float* denseW = (const float*)d_in[2];
    const float* denseb = (const float*)d_in[3];
    const float* d1W    = (const float*)d_in[4];
    const float* d1b    = (const float*)d_in[5];
    const float* d2W    = (const float*)d_in[6];
    const float* d2b    = (const float*)d_in[7];
    const float* convW  = (const float*)d_in[8];
    const float* convb  = (const float*)d_in[9];
    const float* dw1W   = (const float*)d_in[10];
    const float* dw1b   = (const float*)d_in[11];
    const float* dw2W   = (const float*)d_in[12];
    const float* dw2b   = (const float*)d_in[13];
    const float* sdwW   = (const float*)d_in[14];
    const float* sdwb   = (const float*)d_in[15];
    const float* spwW   = (const float*)d_in[16];
    const float* spwb   = (const float*)d_in[17];

    float* rep  = (float*)d_out;                       // [B,P,3]
    float* outp = (float*)d_out + (size_t)BB * PP * 3; // [B,P,128]

    float* ftsd = (float*)d_ws;                                            // B*N*64 f32
    int*   kidx = (int*)((char*)d_ws + (size_t)BB * NN * CIN * sizeof(float)); // B*P*16 i32

    dense_kernel<<<BB * NN / 4, 256, 0, stream>>>(fts, denseW, denseb, ftsd);
    fps_kernel<<<BB, 512, 0, stream>>>(pts, rep);
    knn_kernel<<<BB * PP / 4, 256, 0, stream>>>(pts, rep, kidx);
    xconv_kernel<<<BB * PP, 64, 0, stream>>>(pts, rep, ftsd, kidx,
                                             d1W, d1b, d2W, d2b, convW, convb,
                                             dw1W, dw1b, dw2W, dw2b,
                                             sdwW, sdwb, spwW, spwb, outp);
}

// Round 6
// 2552.049 us; speedup vs baseline: 1.4654x; 1.0248x over previous
//
#include <hip/hip_runtime.h>

#define BB 4
#define NN 8192
#define PP 2048
#define KNB 16
#define CIN 64
#define COUT 128

__device__ __forceinline__ float elu(float x) { return x > 0.0f ? x : expm1f(x); }

// monotone float->uint key (handles negative floats from cancellation)
__device__ __forceinline__ unsigned fkey(float d) {
    unsigned u = __float_as_uint(d);
    unsigned m = (unsigned)((int)u >> 31);
    return u ^ (m | 0x80000000u);
}

// ---------------------------------------------------------------------------
// FPS v5 (current best): 512 threads, 16 idx-ordered pts/thread, LDS mirror,
// one barrier/round, f32-max butterfly + ballot index recovery.
// Exact IEEE ops (no FMA) in distance path to match reference selection.
// ---------------------------------------------------------------------------
__global__ __launch_bounds__(512) void fps_kernel(const float* __restrict__ pts,
                                                  float* __restrict__ rep) {
    const int b = blockIdx.x;
    const int t = threadIdx.x;
    const int lane = t & 63, wave = t >> 6;   // 8 waves

    __shared__ float spx[NN];
    __shared__ float spy[NN];
    __shared__ float spz[NN];
    __shared__ unsigned long long partk[2][8];

    const float* pb = pts + (size_t)b * NN * 3;
    for (int i = t; i < NN; i += 512) {
        spx[i] = pb[3 * i + 0];
        spy[i] = pb[3 * i + 1];
        spz[i] = pb[3 * i + 2];
    }
    __syncthreads();

    float px[16], py[16], pz[16], dist[16];
#pragma unroll
    for (int r = 0; r < 16; ++r) {
        px[r] = spx[t * 16 + r];
        py[r] = spy[t * 16 + r];
        pz[r] = spz[t * 16 + r];
        dist[r] = 1e10f;
    }

    float cx = spx[0], cy = spy[0], cz = spz[0];
    if (t == 0) {
        rep[(size_t)b * PP * 3 + 0] = cx;
        rep[(size_t)b * PP * 3 + 1] = cy;
        rep[(size_t)b * PP * 3 + 2] = cz;
    }

    int buf = 0;
    for (int s = 1; s < PP; ++s) {
        float bv = -1.0f; int bi = 0;
#pragma unroll
        for (int r = 0; r < 16; ++r) {
            float dx = __fsub_rn(px[r], cx);
            float dy = __fsub_rn(py[r], cy);
            float dz = __fsub_rn(pz[r], cz);
            float d = __fadd_rn(__fadd_rn(__fmul_rn(dx, dx), __fmul_rn(dy, dy)), __fmul_rn(dz, dz));
            float nd = fminf(dist[r], d);
            dist[r] = nd;
            bool tk = nd > bv;            // strict >: first-max (lowest r = lowest idx)
            bi = tk ? (t * 16 + r) : bi;
            bv = fmaxf(nd, bv);
        }

        float wmax = bv;
#pragma unroll
        for (int off = 32; off >= 1; off >>= 1)
            wmax = fmaxf(wmax, __shfl_xor(wmax, off));
        unsigned long long mask = __ballot(bv == wmax);
        int wl = __ffsll(mask) - 1;
        int wbi = __shfl(bi, wl);

        if (lane == 0)
            partk[buf][wave] = ((unsigned long long)__float_as_uint(wmax) << 32)
                             | (unsigned)(8191 - wbi);
        __syncthreads();

        unsigned long long kk = partk[buf][0];
#pragma unroll
        for (int q = 1; q < 8; ++q) {
            unsigned long long c = partk[buf][q];
            kk = c > kk ? c : kk;
        }
        int widx = 8191 - (int)(unsigned)(kk & 0xFFFFFFFFULL);
        cx = spx[widx]; cy = spy[widx]; cz = spz[widx];
        if (t == 0) {
            float* rp = rep + ((size_t)b * PP + s) * 3;
            rp[0] = cx; rp[1] = cy; rp[2] = cz;
        }
        buf ^= 1;
    }
}

// ---------------------------------------------------------------------------
// Prep: transpose weights to output-innermost layouts (one-time, tiny).
//   convT[c][k][o]  dw1T/dw2T[i][e]  sdwT[k][e]  spwT[e2][o]
// ---------------------------------------------------------------------------
__global__ __launch_bounds__(256) void prep_kernel(
    const float* __restrict__ convW, const float* __restrict__ dw1W,
    const float* __restrict__ dw2W, const float* __restrict__ sdwW,
    const float* __restrict__ spwW,
    float* __restrict__ convT, float* __restrict__ dw1T, float* __restrict__ dw2T,
    float* __restrict__ sdwT, float* __restrict__ spwT) {
    int i = blockIdx.x * 256 + threadIdx.x;
    if (i < 12288) {                      // convW [o][c][k] -> convT[(c*16+k)*256+o]
        int k = i & 15, c = (i >> 4) % 3, o = i / 48;
        convT[(c * 16 + k) * 256 + o] = convW[i];
    }
    if (i < 4096) {                       // dw[j][m][i] -> T[i*256 + (j*16+m)]
        int ii = i & 15, e = i >> 4;
        dw1T[ii * 256 + e] = dw1W[i];
        dw2T[ii * 256 + e] = dw2W[i];
    }
    if (i < 3072) {                       // sdw[c][m][k] -> T[k*192 + (c*2+m)]
        int k = i & 15, e = i >> 4;
        sdwT[k * 192 + e] = sdwW[i];
    }
    if (i < 24576) {                      // spw[o][e2] -> T[e2*128 + o]
        int e2 = i % 192, o = i / 192;
        spwT[e2 * 128 + o] = spwW[i];
    }
}

// ---------------------------------------------------------------------------
// Dense: fts_d = elu(fts @ W + b). One wave per row, lane = output channel.
// ---------------------------------------------------------------------------
__global__ __launch_bounds__(256) void dense_kernel(const float* __restrict__ fts,
                                                    const float* __restrict__ W,
                                                    const float* __restrict__ bias,
                                                    float* __restrict__ out) {
    const int row = blockIdx.x * 4 + (threadIdx.x >> 6);
    const int c = threadIdx.x & 63;
    float v = fts[(size_t)row * 64 + c];
    float acc = bias[c];
#pragma unroll 8
    for (int k = 0; k < 64; ++k) acc = fmaf(__shfl(v, k), W[k * 64 + c], acc);
    out[(size_t)row * 64 + c] = elu(acc);
}

// ---------------------------------------------------------------------------
// KNN: one wave per rep point; per-lane sorted top-16 of 128 candidates via
// u64 keys (flipped dist bits << 32 | idx); 16-round lex-min merge-extract.
// Exact IEEE ops, same evaluation order as reference: (a - 2b) + c.
// ---------------------------------------------------------------------------
__global__ __launch_bounds__(256) void knn_kernel(const float* __restrict__ pts,
                                                  const float* __restrict__ rep,
                                                  int* __restrict__ kidx) {
    const int wid = blockIdx.x * 4 + (threadIdx.x >> 6);
    const int lane = threadIdx.x & 63;
    const int b = wid >> 11;
    const float* pb = pts + (size_t)b * NN * 3;

    float rx = rep[(size_t)wid * 3 + 0];
    float ry = rep[(size_t)wid * 3 + 1];
    float rz = rep[(size_t)wid * 3 + 2];
    float a = __fadd_rn(__fadd_rn(__fmul_rn(rx, rx), __fmul_rn(ry, ry)), __fmul_rn(rz, rz));

    unsigned long long key[16];
#pragma unroll
    for (int s = 0; s < 16; ++s) key[s] = ~0ULL;

    for (int j = lane; j < NN; j += 64) {
        float qx = pb[j * 3 + 0], qy = pb[j * 3 + 1], qz = pb[j * 3 + 2];
        float cc = __fadd_rn(__fadd_rn(__fmul_rn(qx, qx), __fmul_rn(qy, qy)), __fmul_rn(qz, qz));
        float bs = __fadd_rn(__fadd_rn(__fmul_rn(rx, qx), __fmul_rn(ry, qy)), __fmul_rn(rz, qz));
        float d2 = __fadd_rn(__fsub_rn(a, __fmul_rn(2.0f, bs)), cc);
        unsigned long long nk = ((unsigned long long)fkey(d2) << 32) | (unsigned)j;
        if (nk < key[15]) {
            key[15] = nk;
#pragma unroll
            for (int s2 = 15; s2 > 0; --s2) {
                unsigned long long u = key[s2 - 1], w = key[s2];
                bool sw = w < u;
                key[s2 - 1] = sw ? w : u;
                key[s2] = sw ? u : w;
            }
        }
    }

    int outv = 0;
#pragma unroll 1
    for (int r = 0; r < 16; ++r) {
        unsigned long long h = key[0];
#pragma unroll
        for (int off = 1; off < 64; off <<= 1) {
            unsigned long long o = __shfl_xor(h, off);
            h = (o < h) ? o : h;
        }
        if (lane == r) outv = (int)(unsigned)(h & 0xFFFFFFFFull);
        if (key[0] == h) {  // unique winner (idx embedded in key)
#pragma unroll
            for (int s2 = 0; s2 < 15; ++s2) key[s2] = key[s2 + 1];
            key[15] = ~0ULL;
        }
    }
    if (lane < 16) kidx[(size_t)wid * 16 + lane] = outv;
}

// ---------------------------------------------------------------------------
// XConv + SepConv with transposed (output-innermost) weights: every weight
// load is a coalesced 256B wave read. Per-output summation order identical
// to the previous version -> bitwise-identical results.
// ---------------------------------------------------------------------------
__global__ __launch_bounds__(64) void xconv_kernel(
    const float* __restrict__ pts, const float* __restrict__ rep,
    const float* __restrict__ ftsd, const int* __restrict__ kidx,
    const float* __restrict__ d1W, const float* __restrict__ d1b,
    const float* __restrict__ d2W, const float* __restrict__ d2b,
    const float* __restrict__ convT, const float* __restrict__ convb,
    const float* __restrict__ dw1T, const float* __restrict__ dw1b,
    const float* __restrict__ dw2T, const float* __restrict__ dw2b,
    const float* __restrict__ sdwT, const float* __restrict__ sdwb,
    const float* __restrict__ spwT, const float* __restrict__ spwb,
    float* __restrict__ outp) {
    const int bp = blockIdx.x;
    const int b = bp >> 11;
    const int t = threadIdx.x;

    __shared__ float pl[16][3];
    __shared__ int nidx[16];
    __shared__ float fcat[16][96];   // cols 0..31 = lift, 32..95 = gathered fts_d
    __shared__ float A1[16][32];
    __shared__ float Xm[16][17];
    __shared__ float X2[16][17];
    __shared__ float X3[16][17];
    __shared__ float fX[16][97];
    __shared__ float dsep[192];

    if (t < 16) {
        int id = kidx[(size_t)bp * 16 + t];
        nidx[t] = id;
        const float* q = pts + ((size_t)b * NN + id) * 3;
        const float* rr = rep + (size_t)bp * 3;
        pl[t][0] = q[0] - rr[0];
        pl[t][1] = q[1] - rr[1];
        pl[t][2] = q[2] - rr[2];
    }
    __syncthreads();

    // gather neighbor features (coalesced: lane = channel)
#pragma unroll
    for (int k = 0; k < 16; ++k)
        fcat[k][32 + t] = ftsd[((size_t)b * NN + nidx[k]) * 64 + t];

    // lift MLP layer 1: [16,3] @ [3,32]  (d1W is j-contiguous: already coalesced)
#pragma unroll
    for (int r2 = 0; r2 < 8; ++r2) {
        int e = t + 64 * r2; int k = e >> 5, j = e & 31;
        float acc = d1b[j];
        acc = fmaf(pl[k][0], d1W[j], acc);
        acc = fmaf(pl[k][1], d1W[32 + j], acc);
        acc = fmaf(pl[k][2], d1W[64 + j], acc);
        A1[k][j] = elu(acc);
    }
    __syncthreads();

    // lift MLP layer 2: [16,32] @ [32,32] -> fcat cols 0..31 (j-contiguous)
#pragma unroll
    for (int r2 = 0; r2 < 8; ++r2) {
        int e = t + 64 * r2; int k = e >> 5, j = e & 31;
        float acc = d2b[j];
#pragma unroll
        for (int c = 0; c < 32; ++c) acc = fmaf(A1[k][c], d2W[c * 32 + j], acc);
        fcat[k][j] = elu(acc);
    }
    __syncthreads();

    // X matrix: X[o] = elu(sum_{c,k} pl[k][c]*convT[(c*16+k)*256+o] + convb[o])
    {
        float a0 = convb[t], a1 = convb[t + 64], a2 = convb[t + 128], a3 = convb[t + 192];
#pragma unroll
        for (int c = 0; c < 3; ++c)
#pragma unroll
            for (int k = 0; k < 16; ++k) {
                float p = pl[k][c];
                const float* w = convT + (c * 16 + k) * 256 + t;
                a0 = fmaf(p, w[0],   a0);
                a1 = fmaf(p, w[64],  a1);
                a2 = fmaf(p, w[128], a2);
                a3 = fmaf(p, w[192], a3);
            }
        Xm[t >> 4][t & 15] = elu(a0);
        Xm[(t >> 4) + 4][t & 15] = elu(a1);
        Xm[(t >> 4) + 8][t & 15] = elu(a2);
        Xm[(t >> 4) + 12][t & 15] = elu(a3);
    }
    __syncthreads();

    // dw1: out[j][m] = elu(sum_i Xm[i][j]*dw1T[i*256+e] + dw1b[e]), e=j*16+m
    {
        int m = t & 15, j0 = t >> 4;
        float a0 = dw1b[t], a1 = dw1b[t + 64], a2 = dw1b[t + 128], a3 = dw1b[t + 192];
#pragma unroll
        for (int i = 0; i < 16; ++i) {
            const float* w = dw1T + i * 256 + t;
            a0 = fmaf(Xm[i][j0],      w[0],   a0);
            a1 = fmaf(Xm[i][j0 + 4],  w[64],  a1);
            a2 = fmaf(Xm[i][j0 + 8],  w[128], a2);
            a3 = fmaf(Xm[i][j0 + 12], w[192], a3);
        }
        X2[j0][m] = elu(a0); X2[j0 + 4][m] = elu(a1);
        X2[j0 + 8][m] = elu(a2); X2[j0 + 12][m] = elu(a3);
    }
    __syncthreads();

    // dw2 (no ELU)
    {
        int m = t & 15, j0 = t >> 4;
        float a0 = dw2b[t], a1 = dw2b[t + 64], a2 = dw2b[t + 128], a3 = dw2b[t + 192];
#pragma unroll
        for (int i = 0; i < 16; ++i) {
            const float* w = dw2T + i * 256 + t;
            a0 = fmaf(X2[i][j0],      w[0],   a0);
            a1 = fmaf(X2[i][j0 + 4],  w[64],  a1);
            a2 = fmaf(X2[i][j0 + 8],  w[128], a2);
            a3 = fmaf(X2[i][j0 + 12], w[192], a3);
        }
        X3[j0][m] = a0; X3[j0 + 4][m] = a1;
        X3[j0 + 8][m] = a2; X3[j0 + 12][m] = a3;
    }
    __syncthreads();

    // fts_X[a][c] = sum_b X3[a][b] * fcat[b][c]  (all LDS)
#pragma unroll
    for (int r2 = 0; r2 < 24; ++r2) {
        int e = t + 64 * r2; int a = e & 15, c = e >> 4;
        float acc = 0.0f;
#pragma unroll
        for (int q = 0; q < 16; ++q) acc = fmaf(X3[a][q], fcat[q][c], acc);
        fX[a][c] = acc;
    }
    __syncthreads();

    // separable depthwise: d[e] = sum_k fX[k][c]*sdwT[k*192+e] + sdwb[e], e=c*2+m
    {
        int c0 = t >> 1, c1 = (t + 64) >> 1, c2 = (t + 128) >> 1;
        float a0 = sdwb[t], a1 = sdwb[t + 64], a2 = sdwb[t + 128];
#pragma unroll
        for (int k = 0; k < 16; ++k) {
            const float* w = sdwT + k * 192 + t;
            a0 = fmaf(fX[k][c0], w[0],   a0);
            a1 = fmaf(fX[k][c1], w[64],  a1);
            a2 = fmaf(fX[k][c2], w[128], a2);
        }
        dsep[t] = a0; dsep[t + 64] = a1; dsep[t + 128] = a2;
    }
    __syncthreads();

    // pointwise: out[o] = elu(sum_e2 dsep[e2]*spwT[e2*128+o] + spwb[o])
    {
        float a0 = spwb[t], a1 = spwb[t + 64];
#pragma unroll 16
        for (int e2 = 0; e2 < 192; ++e2) {
            float dv = dsep[e2];
            const float* w = spwT + e2 * 128 + t;
            a0 = fmaf(dv, w[0],  a0);
            a1 = fmaf(dv, w[64], a1);
        }
        outp[(size_t)bp * 128 + t] = elu(a0);
        outp[(size_t)bp * 128 + 64 + t] = elu(a1);
    }
}

extern "C" void kernel_launch(void* const* d_in, const int* in_sizes, int n_in,
                              void* d_out, int out_size, void* d_ws, size_t ws_size,
                              hipStream_t stream) {
    const float* pts    = (const float*)d_in[0];
    const float* fts    = (const float*)d_in[1];
    const float* denseW = (const float*)d_in[2];
    const float* denseb = (const float*)d_in[3];
    const float* d1W    = (const float*)d_in[4];
    const float* d1b    = (const float*)d_in[5];
    const float* d2W    = (const float*)d_in[6];
    const float* d2b    = (const float*)d_in[7];
    const float* convW  = (const float*)d_in[8];
    const float* convb  = (const float*)d_in[9];
    const float* dw1W   = (const float*)d_in[10];
    const float* dw1b   = (const float*)d_in[11];
    const float* dw2W   = (const float*)d_in[12];
    const float* dw2b   = (const float*)d_in[13];
    const float* sdwW   = (const float*)d_in[14];
    const float* sdwb   = (const float*)d_in[15];
    const float* spwW   = (const float*)d_in[16];
    const float* spwb   = (const float*)d_in[17];

    float* rep  = (float*)d_out;                       // [B,P,3]
    float* outp = (float*)d_out + (size_t)BB * PP * 3; // [B,P,128]

    float* ftsd = (float*)d_ws;                                                // 8 MB
    int*   kidx = (int*)((char*)d_ws + (size_t)BB * NN * CIN * sizeof(float)); // 512 KB
    float* wts  = (float*)((char*)d_ws + (size_t)BB * NN * CIN * sizeof(float)
                                       + (size_t)BB * PP * KNB * sizeof(int));
    float* convT = wts;              // 12288
    float* dw1T  = wts + 12288;      // 4096
    float* dw2T  = wts + 16384;      // 4096
    float* sdwT  = wts + 20480;      // 3072
    float* spwT  = wts + 23552;      // 24576  (total 48128 floats = 188 KB)

    prep_kernel<<<96, 256, 0, stream>>>(convW, dw1W, dw2W, sdwW, spwW,
                                        convT, dw1T, dw2T, sdwT, spwT);
    dense_kernel<<<BB * NN / 4, 256, 0, stream>>>(fts, denseW, denseb, ftsd);
    fps_kernel<<<BB, 512, 0, stream>>>(pts, rep);
    knn_kernel<<<BB * PP / 4, 256, 0, stream>>>(pts, rep, kidx);
    xconv_kernel<<<BB * PP, 64, 0, stream>>>(pts, rep, ftsd, kidx,
                                             d1W, d1b, d2W, d2b, convT, convb,
                                             dw1T, dw1b, dw2T, dw2b,
                                             sdwT, sdwb, spwT, spwb, outp);
}